// Round 4
// baseline (599.147 us; speedup 1.0000x reference)
//
#include <hip/hip_runtime.h>
#include <stdint.h>

typedef __attribute__((ext_vector_type(4))) float f32x4;
typedef __attribute__((ext_vector_type(8))) short s16x8;
typedef unsigned int u32;
typedef unsigned short u16;

#define DEVFN static __device__ __forceinline__

constexpr int C = 384;
constexpr int WIMG = 128;
constexpr int HW = 128 * 128;
constexpr float EPS = 1e-5f;
constexpr float QSCALE = 0.17677669529663687f;  // 1/sqrt(32)

// ---- LDS regions (bytes). Total = exactly 160 KiB ----
constexpr int R1 = 0;        // raw-x bf16 [64][384] swz -> Q -> O -> outf(f32, spills into R2/R3)
constexpr int R2 = 49152;    // raw-skip -> VT [384 dh][64 tok] swz
constexpr int R3 = 98304;    // K [64 tok][384] swz
constexpr int PR = 147456;   // 16 KB: LN red/stats (early) | per-wave 2KB strips (attention)
constexpr int LDS_BYTES = 163840;

DEVFN u16 f2bf(float f) {
  union { float f; u32 u; } v; v.f = f;
  u32 r = v.u + 0x7fffu + ((v.u >> 16) & 1u);  // RNE
  return (u16)(r >> 16);
}
DEVFN f32x4 MFMA(s16x8 a, s16x8 b, f32x4 c) {
  return __builtin_amdgcn_mfma_f32_16x16x32_bf16(a, b, c, 0, 0, 0);
}
// XOR-swizzled addresses: row-stride 768B ([64][384] bf16) and 128B ([*][64] bf16)
// swizzle span (bits 4-6, 128B) must not exceed row stride -> bijective.
DEVFN int adr768(int base, int row, int b) { return base + row * 768 + (b ^ ((row & 7) << 4)); }
DEVFN int adr128(int base, int row, int b) { return base + row * 128 + (b ^ ((row & 7) << 4)); }

// ---------------- prep kernels ----------------
__global__ void cvt_bf16_kernel(const float* __restrict__ src, u16* __restrict__ dst, int n) {
  int i = (blockIdx.x * blockDim.x + threadIdx.x) * 4;
  if (i + 3 < n) {
    f32x4 v = *(const f32x4*)(src + i);
    u32* d = (u32*)(dst + i);
    d[0] = (u32)f2bf(v[0]) | ((u32)f2bf(v[1]) << 16);
    d[1] = (u32)f2bf(v[2]) | ((u32)f2bf(v[3]) << 16);
  }
}

// Fold LN gamma (and QSCALE) into weights; emit per-row sums sg = s*sum(W*g), sb = s*sum(W*b)
__global__ void fold_ln_weights(const float* __restrict__ Wq, const float* __restrict__ Wkv,
                                const float* __restrict__ gq, const float* __restrict__ bq,
                                const float* __restrict__ gkv, const float* __restrict__ bkv,
                                u16* __restrict__ wqb, u16* __restrict__ wkb, u16* __restrict__ wvb,
                                float* __restrict__ sg_all, float* __restrict__ sb_all) {
  int r = blockIdx.x * 4 + (threadIdx.x >> 6);  // 1152 rows: Q 0..383, K 384..767, V 768..1151
  int lane = threadIdx.x & 63;
  const float* src; const float* g; const float* b; u16* dst; float scale;
  if (r < 384) { src = Wq + (size_t)r * C; g = gq; b = bq; dst = wqb + (size_t)r * C; scale = QSCALE; }
  else {
    src = Wkv + (size_t)(r - 384) * C; g = gkv; b = bkv; scale = 1.f;
    dst = (r < 768) ? wkb + (size_t)(r - 384) * C : wvb + (size_t)(r - 768) * C;
  }
  float sg = 0.f, sb = 0.f;
#pragma unroll
  for (int i = 0; i < 6; ++i) {
    int c = lane + i * 64;
    float wv = src[c], gg = g[c];
    sg += wv * gg; sb += wv * b[c];
    dst[c] = f2bf(wv * gg * scale);
  }
#pragma unroll
  for (int m = 1; m < 64; m <<= 1) { sg += __shfl_xor(sg, m); sb += __shfl_xor(sb, m); }
  if (lane == 0) { sg_all[r] = sg * scale; sb_all[r] = sb * scale; }
}

// ---------------- fused kernel ----------------
__launch_bounds__(512, 2)
__global__ void fused_win_attn(
    const float* __restrict__ x, const float* __restrict__ skip,
    const u16* __restrict__ wqb, const u16* __restrict__ wkb,
    const u16* __restrict__ wvb, const u16* __restrict__ wob,
    const float* __restrict__ sg_all, const float* __restrict__ sb_all,
    const float* __restrict__ bout, float* __restrict__ out) {
  extern __shared__ char smem[];
  const int tid = threadIdx.x;
  const int lane = tid & 63;
  const int w = tid >> 6;         // wave 0..7
  const int l15 = lane & 15;
  const int lg = lane >> 4;       // 0..3
  const int kco = lg * 8;         // k-chunk short offset within K=32 step

  // bijective XCD swizzle: each XCD gets one batch image (256 consecutive windows)
  const int bid = blockIdx.x;
  const int win = (bid & 7) * 256 + (bid >> 3);
  const int bimg = win >> 8;
  const int Y0 = ((win >> 4) & 15) * 8;
  const int X0 = (win & 15) * 8;
  const size_t img_off = (size_t)bimg * C * HW;

  const f32x4 fzero = {0.f, 0.f, 0.f, 0.f};

  float* red = (float*)(smem + PR);              // [512][2] f32 (LN only)
  float* stats_x = (float*)(smem + PR + 4096);   // [64][2] mean,rstd (until proj epilogues)
  float* stats_s = (float*)(smem + PR + 4608);

  const int p = tid & 63;    // pixel/token 0..63 (row-major y*8+x)
  const int g8 = tid >> 6;   // channel group 0..7 (48 ch each)
  const int yy = p >> 3, xx = p & 7;

  // ---------------- load raw x/skip -> bf16 LDS + LN stats ----------------
  for (int tt = 0; tt < 2; ++tt) {
    const float* src = tt ? skip : x;
    const int RB = tt ? R2 : R1;
    const float* gb = src + img_off + (size_t)(Y0 + yy) * WIMG + X0 + xx;
    float s = 0.f, q = 0.f;
#pragma unroll
    for (int i = 0; i < 24; ++i) {
      int c0 = g8 * 48 + i * 2;
      float v0 = gb[(size_t)c0 * HW];
      float v1 = gb[(size_t)c0 * HW + HW];
      s += v0 + v1; q += v0 * v0 + v1 * v1;
      *(u32*)(smem + adr768(RB, p, c0 * 2)) = (u32)f2bf(v0) | ((u32)f2bf(v1) << 16);
    }
    red[tid * 2] = s; red[tid * 2 + 1] = q;
    __syncthreads();
    if (tid < 64) {
      float sm = 0.f, sq = 0.f;
#pragma unroll
      for (int gg = 0; gg < 8; ++gg) { sm += red[(gg * 64 + tid) * 2]; sq += red[(gg * 64 + tid) * 2 + 1]; }
      float mean = sm * (1.f / 384.f);
      float var = sq * (1.f / 384.f) - mean * mean;
      float* st = tt ? stats_s : stats_x;
      st[tid * 2] = mean; st[tid * 2 + 1] = 1.f / sqrtf(var + EPS);
    }
    __syncthreads();
  }

  // ---------------- K = LN(skip) @ Wk^T  (R2 -> R3), all heads ----------------
  {
    f32x4 acc[3][4];
#pragma unroll
    for (int nn = 0; nn < 3; ++nn)
#pragma unroll
      for (int m = 0; m < 4; ++m) acc[nn][m] = fzero;
#pragma unroll
    for (int k = 0; k < 12; ++k) {
      s16x8 A[4];
#pragma unroll
      for (int m = 0; m < 4; ++m)
        A[m] = *(const s16x8*)(smem + adr768(R2, m * 16 + l15, (k * 32 + kco) * 2));
#pragma unroll
      for (int nn = 0; nn < 3; ++nn) {
        s16x8 B = *(const s16x8*)(wkb + (size_t)((3 * w + nn) * 16 + l15) * C + k * 32 + kco);
#pragma unroll
        for (int m = 0; m < 4; ++m) acc[nn][m] = MFMA(A[m], B, acc[nn][m]);
      }
    }
#pragma unroll
    for (int nn = 0; nn < 3; ++nn) {
      int o = (3 * w + nn) * 16 + l15;
      float sg = sg_all[384 + o], sb = sb_all[384 + o];
#pragma unroll
      for (int m = 0; m < 4; ++m)
#pragma unroll
        for (int j = 0; j < 4; ++j) {
          int tok = m * 16 + lg * 4 + j;
          float mn = stats_s[tok * 2], rs = stats_s[tok * 2 + 1];
          *(u16*)(smem + adr768(R3, tok, o * 2)) = f2bf(rs * acc[nn][m][j] - rs * mn * sg + sb);
        }
    }
  }

  // ---------------- VT read-phase: Wv @ LN(skip)^T -> regs ----------------
  f32x4 accV[3][4];  // [mm = dh-tile][n = tok-tile]
  {
#pragma unroll
    for (int mm = 0; mm < 3; ++mm)
#pragma unroll
      for (int n = 0; n < 4; ++n) accV[mm][n] = fzero;
#pragma unroll
    for (int k = 0; k < 12; ++k) {
      s16x8 Bv[4];
#pragma unroll
      for (int n = 0; n < 4; ++n)
        Bv[n] = *(const s16x8*)(smem + adr768(R2, n * 16 + l15, (k * 32 + kco) * 2));
#pragma unroll
      for (int mm = 0; mm < 3; ++mm) {
        s16x8 A = *(const s16x8*)(wvb + (size_t)((3 * w + mm) * 16 + l15) * C + k * 32 + kco);
#pragma unroll
        for (int n = 0; n < 4; ++n) accV[mm][n] = MFMA(A, Bv[n], accV[mm][n]);
      }
    }
  }

  // ---------------- Q read-phase: LN(x) @ Wq^T * scale -> regs ----------------
  f32x4 accQ[3][4];
  {
#pragma unroll
    for (int nn = 0; nn < 3; ++nn)
#pragma unroll
      for (int m = 0; m < 4; ++m) accQ[nn][m] = fzero;
#pragma unroll
    for (int k = 0; k < 12; ++k) {
      s16x8 A[4];
#pragma unroll
      for (int m = 0; m < 4; ++m)
        A[m] = *(const s16x8*)(smem + adr768(R1, m * 16 + l15, (k * 32 + kco) * 2));
#pragma unroll
      for (int nn = 0; nn < 3; ++nn) {
        s16x8 B = *(const s16x8*)(wqb + (size_t)((3 * w + nn) * 16 + l15) * C + k * 32 + kco);
#pragma unroll
        for (int m = 0; m < 4; ++m) accQ[nn][m] = MFMA(A[m], B, accQ[nn][m]);
      }
    }
  }
  __syncthreads();  // all R1/R2 reads complete; R3 writes globally visible below

  // ---------------- write VT -> R2, Q -> R1 (LN epilogues) ----------------
  {
#pragma unroll
    for (int mm = 0; mm < 3; ++mm)
#pragma unroll
      for (int j = 0; j < 4; ++j) {
        int dh = (3 * w + mm) * 16 + lg * 4 + j;
        float sg = sg_all[768 + dh], sb = sb_all[768 + dh];
#pragma unroll
        for (int n = 0; n < 4; ++n) {
          int tok = n * 16 + l15;
          float mn = stats_s[tok * 2], rs = stats_s[tok * 2 + 1];
          *(u16*)(smem + adr128(R2, dh, tok * 2)) = f2bf(rs * accV[mm][n][j] - rs * mn * sg + sb);
        }
      }
#pragma unroll
    for (int nn = 0; nn < 3; ++nn) {
      int o = (3 * w + nn) * 16 + l15;
      float sg = sg_all[o], sb = sb_all[o];
#pragma unroll
      for (int m = 0; m < 4; ++m)
#pragma unroll
        for (int j = 0; j < 4; ++j) {
          int tok = m * 16 + lg * 4 + j;
          float mn = stats_x[tok * 2], rs = stats_x[tok * 2 + 1];
          *(u16*)(smem + adr768(R1, tok, o * 2)) = f2bf(rs * accQ[nn][m][j] - rs * mn * sg + sb);
        }
    }
  }
  __syncthreads();  // Q/K/VT all visible

  // ---------------- attention: wave = (q-tile, head-half); ZERO barriers ----------------
  const int qt = w & 3;        // q-tile 0..3 (16 q rows each)
  const int hh = w >> 2;       // head half: heads hh*6 .. hh*6+5
  char* strip = smem + PR + w * 2048;  // wave-private scratch (2048 B)
  const int swzq = (l15 & 7) << 4;

  s16x8 oA[6];  // O A-frags per head: lane holds O[q=l15][dh h*32+lg*8..+7]

#pragma unroll
  for (int hloc = 0; hloc < 6; ++hloc) {
    const int h = hh * 6 + hloc;
    // --- S^T = K @ Q^T : lane holds S[kv=m*16+lg*4+j][q=qt*16+l15] ---
    s16x8 bq = *(const s16x8*)(smem + adr768(R1, qt * 16 + l15, h * 64 + lg * 16));
    f32x4 sc[4];
#pragma unroll
    for (int m = 0; m < 4; ++m) {
      s16x8 ak = *(const s16x8*)(smem + adr768(R3, m * 16 + l15, h * 64 + lg * 16));
      sc[m] = MFMA(ak, bq, fzero);
    }
    // --- softmax over kv: 16 in-lane + 2 shfl ---
    float mx = sc[0][0];
#pragma unroll
    for (int m = 0; m < 4; ++m)
#pragma unroll
      for (int j = 0; j < 4; ++j) mx = fmaxf(mx, sc[m][j]);
    mx = fmaxf(mx, __shfl_xor(mx, 16));
    mx = fmaxf(mx, __shfl_xor(mx, 32));
    float ex[4][4];
    float sum = 0.f;
#pragma unroll
    for (int m = 0; m < 4; ++m)
#pragma unroll
      for (int j = 0; j < 4; ++j) { float e = __expf(sc[m][j] - mx); ex[m][j] = e; sum += e; }
    sum += __shfl_xor(sum, 16);
    sum += __shfl_xor(sum, 32);
    float inv = 1.0f / sum;
    // --- write P strip [q=l15][kv], swizzled (wave-local) ---
#pragma unroll
    for (int m = 0; m < 4; ++m)
#pragma unroll
      for (int j2 = 0; j2 < 2; ++j2) {
        u32 pk = (u32)f2bf(ex[m][2 * j2] * inv) | ((u32)f2bf(ex[m][2 * j2 + 1] * inv) << 16);
        *(u32*)(strip + l15 * 128 + ((m * 32 + lg * 8 + j2 * 4) ^ swzq)) = pk;
      }
    // --- PV: O[q][dh] = P @ V, B from VT ---
    f32x4 ov[2] = {fzero, fzero};
#pragma unroll
    for (int ks = 0; ks < 2; ++ks) {
      s16x8 ap = *(const s16x8*)(strip + l15 * 128 + ((ks * 64 + lg * 16) ^ swzq));
#pragma unroll
      for (int n = 0; n < 2; ++n) {
        s16x8 bv = *(const s16x8*)(smem + adr128(R2, h * 32 + n * 16 + l15, ks * 64 + lg * 16));
        ov[n] = MFMA(ap, bv, ov[n]);
      }
    }
    // --- bounce O (C-layout) -> A-layout regs via strip (wave-local) ---
    // row stride 128B >= swizzle span (bits 4-6): bijective (round-3 bug was stride 64)
#pragma unroll
    for (int n = 0; n < 2; ++n)
#pragma unroll
      for (int j = 0; j < 4; ++j) {
        int row = lg * 4 + j;
        *(u16*)(strip + row * 128 + ((n * 32 + l15 * 2) ^ ((row & 7) << 4))) = f2bf(ov[n][j]);
      }
    oA[hloc] = *(const s16x8*)(strip + l15 * 128 + ((lg * 16) ^ swzq));
  }

  // ---------------- write O -> R1 (wave-exclusive bytes: own q-rows x own head cols) ----------------
#pragma unroll
  for (int hloc = 0; hloc < 6; ++hloc)
    *(s16x8*)(smem + adr768(R1, qt * 16 + l15, (hh * 6 + hloc) * 64 + lg * 16)) = oA[hloc];
  __syncthreads();  // O visible to all waves

  // ---------------- out-GEMM: out = O @ Wout^T (+bias later) ----------------
  f32x4 outacc[3][4];
#pragma unroll
  for (int nn = 0; nn < 3; ++nn)
#pragma unroll
    for (int m = 0; m < 4; ++m) outacc[nn][m] = fzero;
#pragma unroll
  for (int k = 0; k < 12; ++k) {
    s16x8 A[4];
#pragma unroll
    for (int m = 0; m < 4; ++m)
      A[m] = *(const s16x8*)(smem + adr768(R1, m * 16 + l15, (k * 32 + kco) * 2));
#pragma unroll
    for (int nn = 0; nn < 3; ++nn) {
      s16x8 B = *(const s16x8*)(wob + (size_t)((3 * w + nn) * 16 + l15) * C + k * 32 + kco);
#pragma unroll
      for (int m = 0; m < 4; ++m) outacc[nn][m] = MFMA(A[m], B, outacc[nn][m]);
    }
  }
  __syncthreads();  // all R1 reads done before outf overlays

  // ---------------- epilogue: bias + transpose via LDS, coalesced store ----------------
  float* outf = (float*)smem;  // f32 [64][385] overlays R1..R3 (dead)
#pragma unroll
  for (int nn = 0; nn < 3; ++nn) {
    int o = (3 * w + nn) * 16 + l15;
    float bo = bout[o];
#pragma unroll
    for (int m = 0; m < 4; ++m)
#pragma unroll
      for (int j = 0; j < 4; ++j)
        outf[(m * 16 + lg * 4 + j) * 385 + o] = outacc[nn][m][j] + bo;
  }
  __syncthreads();
  {
    float* ob = out + img_off + (size_t)(Y0 + yy) * WIMG + X0 + xx;
#pragma unroll
    for (int i = 0; i < 48; ++i) {
      int c = g8 * 48 + i;
      ob[(size_t)c * HW] = outf[p * 385 + c];
    }
  }
}

extern "C" void kernel_launch(void* const* d_in, const int* in_sizes, int n_in,
                              void* d_out, int out_size, void* d_ws, size_t ws_size,
                              hipStream_t stream) {
  const float* x    = (const float*)d_in[0];
  const float* skip = (const float*)d_in[1];
  const float* gq   = (const float*)d_in[2];
  const float* bq   = (const float*)d_in[3];
  const float* gkv  = (const float*)d_in[4];
  const float* bkv  = (const float*)d_in[5];
  const float* Wq   = (const float*)d_in[6];
  const float* Wkv  = (const float*)d_in[7];
  const float* Wout = (const float*)d_in[8];
  const float* bout = (const float*)d_in[9];
  float* out = (float*)d_out;

  char* ws = (char*)d_ws;
  u16* wqb = (u16*)(ws);                  // 384*384 bf16 each
  u16* wkb = (u16*)(ws + 294912);
  u16* wvb = (u16*)(ws + 589824);
  u16* wob = (u16*)(ws + 884736);
  float* sg_all = (float*)(ws + 1179648); // [1152]
  float* sb_all = (float*)(ws + 1184256); // [1152]

  hipFuncSetAttribute((const void*)fused_win_attn,
                      hipFuncAttributeMaxDynamicSharedMemorySize, LDS_BYTES);

  fold_ln_weights<<<288, 256, 0, stream>>>(Wq, Wkv, gq, bq, gkv, bkv, wqb, wkb, wvb, sg_all, sb_all);
  cvt_bf16_kernel<<<144, 256, 0, stream>>>(Wout, wob, 147456);

  fused_win_attn<<<2048, 512, LDS_BYTES, stream>>>(
      x, skip, wqb, wkb, wvb, wob, sg_all, sb_all, bout, out);
}